// Round 1
// baseline (430.481 us; speedup 1.0000x reference)
//
#include <hip/hip_runtime.h>

// Trilinear 3D warp: image [1,1,256,256,256] f32, dvf [1,3,256,256,256] f32
// dvf channels: 0=dy, 1=dx, 2=dz. Layout (H,W,D), D innermost.

constexpr int H = 256, W = 256, D = 256;
constexpr int N = H * W * D;

__global__ __launch_bounds__(256) void warp3d_kernel(
    const float* __restrict__ img,
    const float* __restrict__ dvf,
    float* __restrict__ out)
{
    const int i = blockIdx.x * 256 + threadIdx.x;

    // coalesced dvf stream loads
    const float dy = dvf[i];
    const float dx = dvf[i + N];
    const float dz = dvf[i + 2 * N];

    // decode (y,x,z) from linear index; all dims 256
    const int z = i & (D - 1);
    const int x = (i >> 8) & (W - 1);
    const int y = i >> 16;

    const float ny = (float)y + dy;
    const float nx = (float)x + dx;
    const float nz = (float)z + dz;

    const float fy = floorf(ny);
    const float fx = floorf(nx);
    const float fz = floorf(nz);

    const int iy = (int)fy;
    const int ix = (int)fx;
    const int iz = (int)fz;

    const int y0 = min(max(iy,     0), H - 1);
    const int y1 = min(max(iy + 1, 0), H - 1);
    const int x0 = min(max(ix,     0), W - 1);
    const int x1 = min(max(ix + 1, 0), W - 1);
    const int z0 = min(max(iz,     0), D - 1);
    const int z1 = min(max(iz + 1, 0), D - 1);

    // fractions use the CLIPPED low corner (matches reference exactly)
    const float yd = ny - (float)y0;
    const float xd = nx - (float)x0;
    const float zd = nz - (float)z0;

    const int r00 = (y0 * W + x0) * D;
    const int r01 = (y0 * W + x1) * D;
    const int r10 = (y1 * W + x0) * D;
    const int r11 = (y1 * W + x1) * D;

    const float c000 = img[r00 + z0];
    const float c001 = img[r00 + z1];
    const float c010 = img[r01 + z0];
    const float c011 = img[r01 + z1];
    const float c100 = img[r10 + z0];
    const float c101 = img[r10 + z1];
    const float c110 = img[r11 + z0];
    const float c111 = img[r11 + z1];

    const float omz = 1.0f - zd;
    const float c00 = c000 * omz + c001 * zd;
    const float c01 = c010 * omz + c011 * zd;
    const float c10 = c100 * omz + c101 * zd;
    const float c11 = c110 * omz + c111 * zd;

    const float omx = 1.0f - xd;
    const float c0 = c00 * omx + c01 * xd;
    const float c1 = c10 * omx + c11 * xd;

    out[i] = c0 * (1.0f - yd) + c1 * yd;
}

extern "C" void kernel_launch(void* const* d_in, const int* in_sizes, int n_in,
                              void* d_out, int out_size, void* d_ws, size_t ws_size,
                              hipStream_t stream) {
    const float* img = (const float*)d_in[0];
    const float* dvf = (const float*)d_in[1];
    float* out = (float*)d_out;

    dim3 block(256);
    dim3 grid(N / 256);
    warp3d_kernel<<<grid, block, 0, stream>>>(img, dvf, out);
}

// Round 2
// 422.343 us; speedup vs baseline: 1.0193x; 1.0193x over previous
//
#include <hip/hip_runtime.h>

// Trilinear 3D warp: image [1,1,256,256,256] f32, dvf [1,3,256,256,256] f32
// dvf channels: 0=dy, 1=dx, 2=dz. Layout (H,W,D), D innermost.
//
// R1: fuse each z-pair gather (z0, z1=z0+1) into one float2 load.
// Rationale: kernel is L1-transaction bound (~64 distinct lines per gather
// inst per wave); halving gather instruction count halves transactions.
// Edge cases via zb = min(z0, D-2) + per-value selects:
//   normal   (0<=iz<=254): zb=z0,  c000=v.x, c001=v.y
//   iz < 0   (z0=z1=0)   : zb=0,   c000=v.x, c001=v.x
//   iz >= 255 (z0=z1=255): zb=254, c000=v.y, c001=v.y  (no OOB read)

constexpr int H = 256, W = 256, D = 256;
constexpr int N = H * W * D;

__global__ __launch_bounds__(256) void warp3d_kernel(
    const float* __restrict__ img,
    const float* __restrict__ dvf,
    float* __restrict__ out)
{
    const int i = blockIdx.x * 256 + threadIdx.x;

    // coalesced dvf stream loads
    const float dy = dvf[i];
    const float dx = dvf[i + N];
    const float dz = dvf[i + 2 * N];

    // decode (y,x,z) from linear index; all dims 256
    const int z = i & (D - 1);
    const int x = (i >> 8) & (W - 1);
    const int y = i >> 16;

    const float ny = (float)y + dy;
    const float nx = (float)x + dx;
    const float nz = (float)z + dz;

    const int iy = (int)floorf(ny);
    const int ix = (int)floorf(nx);
    const int iz = (int)floorf(nz);

    const int y0 = min(max(iy,     0), H - 1);
    const int y1 = min(max(iy + 1, 0), H - 1);
    const int x0 = min(max(ix,     0), W - 1);
    const int x1 = min(max(ix + 1, 0), W - 1);
    const int z0 = min(max(iz,     0), D - 1);
    const int z1 = min(max(iz + 1, 0), D - 1);

    // fractions use the CLIPPED low corner (matches reference exactly)
    const float yd = ny - (float)y0;
    const float xd = nx - (float)x0;
    const float zd = nz - (float)z0;

    const int zb = min(z0, D - 2);
    const bool lo = (z0 == zb);       // low corner is v.x
    const bool hi = (z1 == zb + 1);   // high corner is v.y

    const int r00 = (y0 * W + x0) * D + zb;
    const int r01 = (y0 * W + x1) * D + zb;
    const int r10 = (y1 * W + x0) * D + zb;
    const int r11 = (y1 * W + x1) * D + zb;

    // one 8B gather per row (4B-aligned; gfx950 global unaligned access OK)
    const float2 v00 = *reinterpret_cast<const float2*>(img + r00);
    const float2 v01 = *reinterpret_cast<const float2*>(img + r01);
    const float2 v10 = *reinterpret_cast<const float2*>(img + r10);
    const float2 v11 = *reinterpret_cast<const float2*>(img + r11);

    const float c000 = lo ? v00.x : v00.y;
    const float c001 = hi ? v00.y : v00.x;
    const float c010 = lo ? v01.x : v01.y;
    const float c011 = hi ? v01.y : v01.x;
    const float c100 = lo ? v10.x : v10.y;
    const float c101 = hi ? v10.y : v10.x;
    const float c110 = lo ? v11.x : v11.y;
    const float c111 = hi ? v11.y : v11.x;

    const float omz = 1.0f - zd;
    const float c00 = c000 * omz + c001 * zd;
    const float c01 = c010 * omz + c011 * zd;
    const float c10 = c100 * omz + c101 * zd;
    const float c11 = c110 * omz + c111 * zd;

    const float omx = 1.0f - xd;
    const float c0 = c00 * omx + c01 * xd;
    const float c1 = c10 * omx + c11 * xd;

    out[i] = c0 * (1.0f - yd) + c1 * yd;
}

extern "C" void kernel_launch(void* const* d_in, const int* in_sizes, int n_in,
                              void* d_out, int out_size, void* d_ws, size_t ws_size,
                              hipStream_t stream) {
    const float* img = (const float*)d_in[0];
    const float* dvf = (const float*)d_in[1];
    float* out = (float*)d_out;

    dim3 block(256);
    dim3 grid(N / 256);
    warp3d_kernel<<<grid, block, 0, stream>>>(img, dvf, out);
}